// Round 2
// baseline (189.075 us; speedup 1.0000x reference)
//
#include <hip/hip_runtime.h>

// KANvolution: B=4, H=W=66, C=32, F=64, KH=KW=3, Ho=Wo=64, 17 control points.
// grid spacing h = 2/16 = 0.125 ; basis = hat(k), hat(k+1) with weights (1-t, t).

#define NCIJ 288      // C*KH*KW
#define NF   64
#define TROW 18       // 17 folded control points + 1 w_silu
#define CH   18       // cij per LDS chunk
#define NCHUNK (NCIJ / CH)   // 16

// Build T[cij][f][18] = { w_spline[f,cij] * cp[f,cij,g] (g=0..16), w_silu[f,cij] }
__global__ void build_table(const float* __restrict__ cp,
                            const float* __restrict__ wsp,
                            const float* __restrict__ wsl,
                            float* __restrict__ T) {
    int p = blockIdx.x * blockDim.x + threadIdx.x;   // p = cij*64 + f
    if (p >= NCIJ * NF) return;
    int cij = p >> 6, f = p & 63;
    const float* src = cp + ((size_t)f * NCIJ + cij) * 17;
    float s = wsp[f * NCIJ + cij];
    float* dst = T + (size_t)p * TROW;
    #pragma unroll
    for (int g = 0; g < 17; ++g) dst[g] = s * src[g];
    dst[17] = wsl[f * NCIJ + cij];
}

// 256 blocks = (b, ty, tx) 8x8 output tiles; 512 threads = 8 waves.
// lane = output pixel within 8x8 tile; wave w owns filters f0 = 8*w .. 8*w+7.
__global__ __launch_bounds__(512, 1)
void kan_conv(const float* __restrict__ x, const float* __restrict__ T,
              const float* __restrict__ bias, float* __restrict__ out) {
    __shared__ float xs[32 * 100];                    // x tile, [c][r*10+col]
    __shared__ __align__(16) float tab[CH * NF * TROW];

    int tid = threadIdx.x;
    int lane = tid & 63, w = tid >> 6;
    int f0 = w << 3;
    int dy = lane >> 3, dx = lane & 7;
    int bid = blockIdx.x;
    int b = bid >> 6, ty = (bid >> 3) & 7, tx = bid & 7;
    int ho0 = ty << 3, wo0 = tx << 3;

    // stage x tile: 10x10 spatial halo x 32 channels, transposed to channel-major
    for (int e = tid; e < 3200; e += 512) {
        int c = e & 31, rc = e >> 5;                  // rc in 0..99
        int r = rc / 10, col = rc - r * 10;
        xs[c * 100 + rc] = x[(((b * 66) + ho0 + r) * 66 + (wo0 + col)) * 32 + c];
    }

    float acc[8];
    #pragma unroll
    for (int ff = 0; ff < 8; ++ff) acc[ff] = bias[f0 + ff];

    for (int chunk = 0; chunk < NCHUNK; ++chunk) {
        __syncthreads();                              // prior compute done (covers xs too)
        const float4* src = (const float4*)(T + (size_t)chunk * CH * NF * TROW);
        float4* dstv = (float4*)tab;
        for (int e = tid; e < CH * NF * TROW / 4; e += 512) dstv[e] = src[e];
        __syncthreads();                              // tab ready
        #pragma unroll 1
        for (int cc = 0; cc < CH; ++cc) {
            int cij = chunk * CH + cc;
            int c = cij / 9, ij = cij - c * 9;
            int i = ij / 3, j = ij - i * 3;
            float xv = xs[c * 100 + (dy + i) * 10 + (dx + j)];
            float xc = fminf(fmaxf(xv, -1.f), 1.f);
            float u = (xc + 1.f) * 8.f;               // in [0,16]
            int k = (int)u; if (k > 15) k = 15;
            float t = u - (float)k;
            float a0 = 1.f - t;
            float sl = xv / (1.f + __expf(-xv));      // SiLU
            const float* row = &tab[(cc * NF + f0) * TROW + k];
            const float* rowe = &tab[(cc * NF + f0) * TROW + 17];
            #pragma unroll
            for (int ff = 0; ff < 8; ++ff) {
                float cpk  = row[ff * TROW];          // ds_read2_b32 pair
                float cpk1 = row[ff * TROW + 1];
                float ws   = rowe[ff * TROW];         // uniform addr -> broadcast
                acc[ff] += a0 * cpk + t * cpk1 + sl * ws;
            }
        }
    }

    size_t base = ((((size_t)b * 64 + (ho0 + dy)) * 64 + (wo0 + dx)) * 64) + f0;
    float4 o0 = make_float4(acc[0], acc[1], acc[2], acc[3]);
    float4 o1 = make_float4(acc[4], acc[5], acc[6], acc[7]);
    *(float4*)(out + base)     = o0;
    *(float4*)(out + base + 4) = o1;
}

extern "C" void kernel_launch(void* const* d_in, const int* in_sizes, int n_in,
                              void* d_out, int out_size, void* d_ws, size_t ws_size,
                              hipStream_t stream) {
    const float* x    = (const float*)d_in[0];
    const float* cp   = (const float*)d_in[1];
    const float* wsp  = (const float*)d_in[2];
    const float* wsl  = (const float*)d_in[3];
    const float* bias = (const float*)d_in[4];
    float* out = (float*)d_out;
    float* T   = (float*)d_ws;   // needs 288*64*18*4 = 1,327,104 B

    hipLaunchKernelGGL(build_table, dim3((NCIJ * NF + 255) / 256), dim3(256), 0, stream,
                       cp, wsp, wsl, T);
    hipLaunchKernelGGL(kan_conv, dim3(256), dim3(512), 0, stream,
                       x, T, bias, out);
}

// Round 4
// 140.924 us; speedup vs baseline: 1.3417x; 1.3417x over previous
//
#include <hip/hip_runtime.h>

// KANvolution: B=4, H=W=66, C=32, F=64, KH=KW=3, Ho=Wo=64, 17 control points.
// Spline = 2-point lerp: k = floor((clip(x)+1)*8), t = frac; eps-normalization is a no-op.
//
// Table layout in d_ws (pre-swizzled at build time):
//   Tsp: uint (f16x2 pair (cp_eff[k], cp_eff[k+1])) at word
//        W(f,cij,k) = ((f>>5)*288 + cij)*512 + k*32 + ((f&31) ^ ((k&7)<<2))
//        -> one ds_read_b128 covers 4 consecutive f; XOR swizzle gives 8 bank-slots,
//           2 addrs/bank for k in 0..15 => conflict-free (2-way is free).
//   Tws: float w_silu at ((f>>5)*288 + cij)*32 + (f&31), after Tsp (294912 dwords).

#define NCIJ 288
#define CH   18            // cij per LDS chunk (2 channels x 9 taps)
#define NCHUNK 16
#define SPW  0             // LDS dword offsets
#define WVW  (CH*16*32)    // 9216
#define XSW  (WVW + CH*32) // 9792
#define TOTW (XSW + 3200)  // 12992 dwords = 51968 B

typedef _Float16 half2_t __attribute__((ext_vector_type(2)));
typedef __fp16   fp16x2_t __attribute__((ext_vector_type(2)));
union h2u { half2_t h; fp16x2_t f; uint u; };

// ---- build: one block per cij, 256 threads ----
__global__ __launch_bounds__(256)
void build_table(const float* __restrict__ cp, const float* __restrict__ wsp,
                 const float* __restrict__ wsl, uint* __restrict__ Tsp,
                 float* __restrict__ Tws) {
    __shared__ float L[64 * 19];   // [f][g 0..16], stride 19 (odd) = conflict-free
    __shared__ float Lw[64], Ls[64];
    int cij = blockIdx.x, t = threadIdx.x;
    for (int e = t; e < 64 * 17; e += 256) {
        int f = e / 17, g = e - f * 17;
        L[f * 19 + g] = cp[((size_t)f * NCIJ + cij) * 17 + g];
    }
    if (t < 64) {
        Lw[t] = wsl[t * NCIJ + cij];
        Ls[t] = wsp[t * NCIJ + cij];
    }
    __syncthreads();
    int f = t & 63;
    float s = Ls[f];
    #pragma unroll
    for (int kk = 0; kk < 4; ++kk) {
        int k = (t >> 6) * 4 + kk;
        h2u cv;
        cv.f = __builtin_amdgcn_cvt_pkrtz(s * L[f * 19 + k], s * L[f * 19 + k + 1]);
        int word = (((f >> 5) * NCIJ) + cij) * 512 + k * 32 + ((f & 31) ^ ((k & 7) << 2));
        Tsp[word] = cv.u;
    }
    if (t < 64) Tws[((t >> 5) * NCIJ + cij) * 32 + (t & 31)] = Lw[t];
}

// ---- main: 512 blocks (tile, fhalf) x 512 threads (8 waves, 4 f/wave) ----
__global__ __launch_bounds__(512, 4)
void kan_conv(const float* __restrict__ x, const uint* __restrict__ Tsp,
              const float* __restrict__ Tws, const float* __restrict__ bias,
              float* __restrict__ out) {
    __shared__ uint shm[TOTW];

    int tid = threadIdx.x;
    int lane = tid & 63, w = tid >> 6;
    int q = w << 2;                        // f-quarter within the 32-f half
    int dy = lane >> 3, dx = lane & 7;
    int fh = blockIdx.x >> 8;              // 0/1 filter half
    int tile = blockIdx.x & 255;
    int b = tile >> 6, ty = (tile >> 3) & 7, tx = tile & 7;
    int ho0 = ty << 3, wo0 = tx << 3;

    // stage x tile: 10x10 halo x 32 channels, channel-major [c][r*10+col]
    for (int e = tid; e < 3200; e += 512) {
        int c = e & 31, rc = e >> 5;
        int r = rc / 10, col = rc - r * 10;
        shm[XSW + c * 100 + rc] =
            __float_as_uint(x[(((b * 66) + ho0 + r) * 66 + (wo0 + col)) * 32 + c]);
    }

    float acc[4];
    #pragma unroll
    for (int ff = 0; ff < 4; ++ff) acc[ff] = bias[fh * 32 + q + ff];

    int xb0 = XSW + dy * 10 + dx;
    int q4swz = q;                         // word-level f offset for this wave

    for (int ch = 0; ch < NCHUNK; ++ch) {
        __syncthreads();
        {   // stage table chunk: sp (2304 uint4) then wv (144 uint4), contiguous in LDS
            const uint4* s1 = (const uint4*)(Tsp + ((size_t)(fh * NCIJ + ch * CH)) * 512);
            const uint4* s2 = (const uint4*)(Tws + ((size_t)(fh * NCIJ + ch * CH)) * 32);
            uint4* d = (uint4*)shm;
            for (int e = tid; e < 2448; e += 512)
                d[e] = (e < 2304) ? s1[e] : s2[e - 2304];
        }
        __syncthreads();

        int xb = xb0 + ch * 200;
        #pragma unroll
        for (int c2 = 0; c2 < 2; ++c2) {
            #pragma unroll
            for (int i = 0; i < 3; ++i) {
                #pragma unroll
                for (int j = 0; j < 3; ++j) {
                    const int cc = c2 * 9 + i * 3 + j;
                    float xv = __uint_as_float(shm[xb + c2 * 100 + i * 10 + j]);
                    float xc = fminf(fmaxf(xv, -1.f), 1.f);
                    float u = fmaf(xc, 8.f, 8.f);          // in [0,16]
                    int k = (int)u; k = (k > 15) ? 15 : k;
                    float t = u - (float)k;
                    float sl = xv * __builtin_amdgcn_rcpf(1.f + __expf(-xv));
                    int widx = SPW + cc * 512 + k * 32 + (q4swz ^ ((k & 7) << 2));
                    uint4 pr = *(const uint4*)&shm[widx];          // 4 f16x2 pairs
                    float4 wsv = *(const float4*)&shm[WVW + cc * 32 + q];
#if __has_builtin(__builtin_amdgcn_fdot2)
                    h2u atu; atu.f = __builtin_amdgcn_cvt_pkrtz(1.f - t, t);
                    h2u c0, c1, c2u, c3;
                    c0.u = pr.x; c1.u = pr.y; c2u.u = pr.z; c3.u = pr.w;
                    acc[0] = __builtin_amdgcn_fdot2(atu.h, c0.h, acc[0], false);
                    acc[1] = __builtin_amdgcn_fdot2(atu.h, c1.h, acc[1], false);
                    acc[2] = __builtin_amdgcn_fdot2(atu.h, c2u.h, acc[2], false);
                    acc[3] = __builtin_amdgcn_fdot2(atu.h, c3.h, acc[3], false);
#else
                    float a0 = 1.f - t;
                    uint prs[4] = {pr.x, pr.y, pr.z, pr.w};
                    #pragma unroll
                    for (int ff = 0; ff < 4; ++ff) {
                        h2u cv; cv.u = prs[ff];
                        acc[ff] = fmaf(a0, (float)cv.h.x, fmaf(t, (float)cv.h.y, acc[ff]));
                    }
#endif
                    acc[0] = fmaf(sl, wsv.x, acc[0]);
                    acc[1] = fmaf(sl, wsv.y, acc[1]);
                    acc[2] = fmaf(sl, wsv.z, acc[2]);
                    acc[3] = fmaf(sl, wsv.w, acc[3]);
                }
            }
        }
    }

    size_t base = ((((size_t)b * 64 + (ho0 + dy)) * 64 + (wo0 + dx)) * 64) + fh * 32 + q;
    *(float4*)(out + base) = make_float4(acc[0], acc[1], acc[2], acc[3]);
}

extern "C" void kernel_launch(void* const* d_in, const int* in_sizes, int n_in,
                              void* d_out, int out_size, void* d_ws, size_t ws_size,
                              hipStream_t stream) {
    const float* x    = (const float*)d_in[0];
    const float* cp   = (const float*)d_in[1];
    const float* wsp  = (const float*)d_in[2];
    const float* wsl  = (const float*)d_in[3];
    const float* bias = (const float*)d_in[4];
    float* out = (float*)d_out;
    uint*  Tsp = (uint*)d_ws;                       // 2*288*16*32 = 294912 dwords
    float* Tws = (float*)d_ws + 294912;             // 2*288*32   =  18432 dwords

    hipLaunchKernelGGL(build_table, dim3(NCIJ), dim3(256), 0, stream,
                       cp, wsp, wsl, Tsp, Tws);
    hipLaunchKernelGGL(kan_conv, dim3(512), dim3(512), 0, stream,
                       x, Tsp, Tws, bias, out);
}